// Round 7
// baseline (973.015 us; speedup 1.0000x reference)
//
#include <hip/hip_runtime.h>
#include <math.h>

#define BB   64
#define NIN  512
#define NH   512
#define TT   512

typedef _Float16 half2_t __attribute__((ext_vector_type(2)));
typedef _Float16 half8_t __attribute__((ext_vector_type(8)));
typedef float    f32x4  __attribute__((ext_vector_type(4)));

__device__ __forceinline__ unsigned pk16(float x, float y) {
    unsigned lo = (unsigned)__builtin_bit_cast(unsigned short, (_Float16)x);
    unsigned hi = (unsigned)__builtin_bit_cast(unsigned short, (_Float16)y);
    return lo | (hi << 16);
}

__device__ __forceinline__ float dot2u(unsigned w, unsigned a, float acc) {
    return __builtin_amdgcn_fdot2(__builtin_bit_cast(half2_t, w),
                                  __builtin_bit_cast(half2_t, a), acc, false);
}

__device__ __forceinline__ float tanh_fast(float x) {
    float ax = __builtin_fabsf(x);
    float e  = __builtin_amdgcn_exp2f(-2.885390082f * ax);   // exp(-2|x|)
    float r  = (1.0f - e) * __builtin_amdgcn_rcpf(1.0f + e);
    return __builtin_copysignf(r, x);
}

// ---------------------------------------------------------------------------
// K0: pack X and Wax into half2-pair dwords (unchanged, verified).
// ---------------------------------------------------------------------------
#define NX4 (BB * (NIN / 2) * (TT / 4))
#define NW4 ((NIN / 2) * (NH / 4))

__global__ __launch_bounds__(256) void pack_f16(
    const float* __restrict__ X, const float* __restrict__ Wax,
    unsigned* __restrict__ Xp, unsigned* __restrict__ Wp)
{
    const int gid = blockIdx.x * 256 + threadIdx.x;
    if (gid < NX4) {
        const int t4 = gid & (TT / 4 - 1);
        const int pr = gid >> 7;
        const int j  = pr & (NIN / 2 - 1);
        const int b  = pr >> 8;
        float4 r0 = *(const float4*)&X[((size_t)b * NIN + 2 * j    ) * TT + t4 * 4];
        float4 r1 = *(const float4*)&X[((size_t)b * NIN + 2 * j + 1) * TT + t4 * 4];
        uint4 o;
        o.x = pk16(r0.x, r1.x); o.y = pk16(r0.y, r1.y);
        o.z = pk16(r0.z, r1.z); o.w = pk16(r0.w, r1.w);
        *(uint4*)&Xp[(size_t)pr * TT + t4 * 4] = o;
    } else {
        const int g = gid - NX4;
        if (g < NW4) {
            const int h4 = g & (NH / 4 - 1);
            const int j  = g >> 7;
            float4 r0 = *(const float4*)&Wax[((size_t)(2 * j    )) * NH + h4 * 4];
            float4 r1 = *(const float4*)&Wax[((size_t)(2 * j + 1)) * NH + h4 * 4];
            uint4 o;
            o.x = pk16(r0.x, r1.x); o.y = pk16(r0.y, r1.y);
            o.z = pk16(r0.z, r1.z); o.w = pk16(r0.w, r1.w);
            *(uint4*)&Wp[(size_t)j * NH + h4 * 4] = o;
        }
    }
}

// ---------------------------------------------------------------------------
// K1' (MFMA, packed inputs) — unchanged, verified.
// ---------------------------------------------------------------------------
__global__ __launch_bounds__(256) void inp_proj_mfma_pk(
    const unsigned* __restrict__ Xp, const unsigned* __restrict__ Wp,
    const float* __restrict__ bx, const float* __restrict__ ba,
    float* __restrict__ out)
{
    __shared__ unsigned Xsp[16][132];
    __shared__ unsigned Wsp[16][132];

    const int b   = blockIdx.z;
    const int t0  = blockIdx.y * 128;
    const int h0  = blockIdx.x * 128;
    const int tid = threadIdx.x;
    const int lane = tid & 63;
    const int wid  = tid >> 6;
    const int wm   = wid >> 1;
    const int wn   = wid & 1;
    const int q    = lane >> 4;
    const int r16  = lane & 15;

    const int lr = tid >> 4;
    const int lc = (tid & 15) * 8;

    const unsigned* Xb = Xp + (size_t)b * (NIN / 2) * TT;

    f32x4 acc[4][4] = {};

    for (int p0 = 0; p0 < NIN / 2; p0 += 16) {
        const unsigned* Arow = &Xb[(size_t)(p0 + lr) * TT + t0 + lc];
        const unsigned* Brow = &Wp[(size_t)(p0 + lr) * NH + h0 + lc];
        uint4 xa = *(const uint4*)&Arow[0];
        uint4 xb = *(const uint4*)&Arow[4];
        uint4 wa = *(const uint4*)&Brow[0];
        uint4 wb = *(const uint4*)&Brow[4];

        __syncthreads();
        *(uint4*)&Xsp[lr][lc]     = xa;
        *(uint4*)&Xsp[lr][lc + 4] = xb;
        *(uint4*)&Wsp[lr][lc]     = wa;
        *(uint4*)&Wsp[lr][lc + 4] = wb;
        __syncthreads();

        uint4 af[4], bf[4];
#pragma unroll
        for (int mt = 0; mt < 4; ++mt) {
            const int tc = wm * 64 + mt * 16 + r16;
            af[mt].x = Xsp[4 * q + 0][tc];
            af[mt].y = Xsp[4 * q + 1][tc];
            af[mt].z = Xsp[4 * q + 2][tc];
            af[mt].w = Xsp[4 * q + 3][tc];
        }
#pragma unroll
        for (int nt = 0; nt < 4; ++nt) {
            const int hc = wn * 64 + nt * 16 + r16;
            bf[nt].x = Wsp[4 * q + 0][hc];
            bf[nt].y = Wsp[4 * q + 1][hc];
            bf[nt].z = Wsp[4 * q + 2][hc];
            bf[nt].w = Wsp[4 * q + 3][hc];
        }
#pragma unroll
        for (int mt = 0; mt < 4; ++mt)
#pragma unroll
            for (int nt = 0; nt < 4; ++nt)
                acc[mt][nt] = __builtin_amdgcn_mfma_f32_16x16x32_f16(
                    __builtin_bit_cast(half8_t, af[mt]),
                    __builtin_bit_cast(half8_t, bf[nt]),
                    acc[mt][nt], 0, 0, 0);
    }

#pragma unroll
    for (int nt = 0; nt < 4; ++nt) {
        const int h = h0 + wn * 64 + nt * 16 + r16;
        const float bias = bx[h] + ba[h];
#pragma unroll
        for (int mt = 0; mt < 4; ++mt) {
            const int trow = t0 + wm * 64 + mt * 16 + q * 4;
#pragma unroll
            for (int rr = 0; rr < 4; ++rr) {
                out[(size_t)(trow + rr) * (BB * NH) + (size_t)b * NH + h] =
                    acc[mt][nt][rr] + bias;
            }
        }
    }
}

// ---------------------------------------------------------------------------
// K1 fallback (f32 inputs) — used only if ws too small. Unchanged.
// ---------------------------------------------------------------------------
__global__ __launch_bounds__(256) void inp_proj_mfma(
    const float* __restrict__ X, const float* __restrict__ Wax,
    const float* __restrict__ bx, const float* __restrict__ ba,
    float* __restrict__ out)
{
    __shared__ unsigned Xsp[16][132];
    __shared__ unsigned Wsp[16][132];

    const int b   = blockIdx.z;
    const int t0  = blockIdx.y * 128;
    const int h0  = blockIdx.x * 128;
    const int tid = threadIdx.x;
    const int lane = tid & 63;
    const int wid  = tid >> 6;
    const int wm   = wid >> 1;
    const int wn   = wid & 1;
    const int q    = lane >> 4;
    const int r16  = lane & 15;

    const int lr = tid >> 4;
    const int lc = (tid & 15) * 8;

    const float* Xb = X + (size_t)b * NIN * TT;

    f32x4 acc[4][4] = {};

    for (int i0 = 0; i0 < NIN; i0 += 32) {
        const int k0 = i0 + 2 * lr, k1 = k0 + 1;
        float4 xa0 = *(const float4*)&Xb[(size_t)k0 * TT + t0 + lc];
        float4 xa1 = *(const float4*)&Xb[(size_t)k0 * TT + t0 + lc + 4];
        float4 xb0 = *(const float4*)&Xb[(size_t)k1 * TT + t0 + lc];
        float4 xb1 = *(const float4*)&Xb[(size_t)k1 * TT + t0 + lc + 4];
        float4 wa0 = *(const float4*)&Wax[(size_t)k0 * NH + h0 + lc];
        float4 wa1 = *(const float4*)&Wax[(size_t)k0 * NH + h0 + lc + 4];
        float4 wb0 = *(const float4*)&Wax[(size_t)k1 * NH + h0 + lc];
        float4 wb1 = *(const float4*)&Wax[(size_t)k1 * NH + h0 + lc + 4];

        uint4 xp0, xp1, wp0, wp1;
        xp0.x = pk16(xa0.x, xb0.x); xp0.y = pk16(xa0.y, xb0.y);
        xp0.z = pk16(xa0.z, xb0.z); xp0.w = pk16(xa0.w, xb0.w);
        xp1.x = pk16(xa1.x, xb1.x); xp1.y = pk16(xa1.y, xb1.y);
        xp1.z = pk16(xa1.z, xb1.z); xp1.w = pk16(xa1.w, xb1.w);
        wp0.x = pk16(wa0.x, wb0.x); wp0.y = pk16(wa0.y, wb0.y);
        wp0.z = pk16(wa0.z, wb0.z); wp0.w = pk16(wa0.w, wb0.w);
        wp1.x = pk16(wa1.x, wb1.x); wp1.y = pk16(wa1.y, wb1.y);
        wp1.z = pk16(wa1.z, wb1.z); wp1.w = pk16(wa1.w, wb1.w);

        __syncthreads();
        *(uint4*)&Xsp[lr][lc]     = xp0;
        *(uint4*)&Xsp[lr][lc + 4] = xp1;
        *(uint4*)&Wsp[lr][lc]     = wp0;
        *(uint4*)&Wsp[lr][lc + 4] = wp1;
        __syncthreads();

        uint4 af[4], bf[4];
#pragma unroll
        for (int mt = 0; mt < 4; ++mt) {
            const int tc = wm * 64 + mt * 16 + r16;
            af[mt].x = Xsp[4 * q + 0][tc];
            af[mt].y = Xsp[4 * q + 1][tc];
            af[mt].z = Xsp[4 * q + 2][tc];
            af[mt].w = Xsp[4 * q + 3][tc];
        }
#pragma unroll
        for (int nt = 0; nt < 4; ++nt) {
            const int hc = wn * 64 + nt * 16 + r16;
            bf[nt].x = Wsp[4 * q + 0][hc];
            bf[nt].y = Wsp[4 * q + 1][hc];
            bf[nt].z = Wsp[4 * q + 2][hc];
            bf[nt].w = Wsp[4 * q + 3][hc];
        }
#pragma unroll
        for (int mt = 0; mt < 4; ++mt)
#pragma unroll
            for (int nt = 0; nt < 4; ++nt)
                acc[mt][nt] = __builtin_amdgcn_mfma_f32_16x16x32_f16(
                    __builtin_bit_cast(half8_t, af[mt]),
                    __builtin_bit_cast(half8_t, bf[nt]),
                    acc[mt][nt], 0, 0, 0);
    }

#pragma unroll
    for (int nt = 0; nt < 4; ++nt) {
        const int h = h0 + wn * 64 + nt * 16 + r16;
        const float bias = bx[h] + ba[h];
#pragma unroll
        for (int mt = 0; mt < 4; ++mt) {
            const int trow = t0 + wm * 64 + mt * 16 + q * 4;
#pragma unroll
            for (int rr = 0; rr < 4; ++rr) {
                out[(size_t)(trow + rr) * (BB * NH) + (size_t)b * NH + h] =
                    acc[mt][nt][rr] + bias;
            }
        }
    }
}

// ---------------------------------------------------------------------------
// K2 v10 (HYBRID pipe-split scan): one block per batch, 16 waves.
//   Waves 0-7  (tid<512): v9's MFMA engine, cols 0..255 (2 N-tiles/wave,
//     full K via 32 chained 16x16x32 MFMAs; B-frags RKT=12 reg + LKT=4 LDS).
//     256 MFMA/CU/step -> ~1240 cyc matrix pipe (half of v9's 2484 floor).
//   Waves 8-15 (tid>=512): v6's dot2 engine, cols 256..511 (k-eighth split,
//     4 cols/thread, NRP=24 reg + NLP=8 LDS pairs, readlane broadcast,
//     part[] LDS reduce by t2<256). Runs on the VALU pipe CONCURRENTLY.
// Shared: double-buffered a_h halves (2 KB), v6's proven 2-barrier protocol
// (both branches execute identical barrier counts; wave-uniform branch).
// ---------------------------------------------------------------------------
#define RKT 12   // MFMA half: register-resident K-tiles (of 16)
#define LKT 4    // MFMA half: LDS-resident K-tiles
#define NRP 24   // dot2 half: register-resident pairs per column
#define NLP 8    // dot2 half: LDS-resident pairs per column

__device__ __forceinline__ unsigned bline(unsigned a, int l) {
    return (unsigned)__builtin_amdgcn_readlane((int)a, l);
}

__global__ __launch_bounds__(1024, 4) void rnn_scan_v10(
    const float* __restrict__ Waa, float* __restrict__ out)
{
    __shared__ uint4    wldsA[LKT * 2][512];   // 64 KB  MFMA B-frags
    __shared__ uint4    wlds2[NLP][512];       // 64 KB  dot2 weights (4 cols)
    __shared__ unsigned short a_h[2][NH];      // 2 KB   a_t halves, dbuf
    __shared__ float    part[8][260];          // 8.1 KB dot2 k-partials

    const int tid = threadIdx.x;
    const int b   = blockIdx.x;

    if (tid < 256) *(unsigned*)&a_h[0][tid * 2] = 0u;   // a_0 = 0

    if (tid < 512) {
        // ================= MFMA half: cols 0..255 =================
        const int w2 = tid >> 6;             // wave 0..7
        const int l  = tid & 63;
        const int q  = l >> 4;               // k-subgroup 0..3
        const int c0 = w2 * 32 + (l & 15);   // first column (<256)
        const int c1 = c0 + 16;              // second column

        uint4 br0[RKT], br1[RKT];
#pragma unroll
        for (int kk = 0; kk < RKT; ++kk) {
            const int kb = kk * 32 + 8 * q;
            uint4 v0, v1;
            v0.x = pk16(Waa[(size_t)(kb + 0) * NH + c0], Waa[(size_t)(kb + 1) * NH + c0]);
            v0.y = pk16(Waa[(size_t)(kb + 2) * NH + c0], Waa[(size_t)(kb + 3) * NH + c0]);
            v0.z = pk16(Waa[(size_t)(kb + 4) * NH + c0], Waa[(size_t)(kb + 5) * NH + c0]);
            v0.w = pk16(Waa[(size_t)(kb + 6) * NH + c0], Waa[(size_t)(kb + 7) * NH + c0]);
            v1.x = pk16(Waa[(size_t)(kb + 0) * NH + c1], Waa[(size_t)(kb + 1) * NH + c1]);
            v1.y = pk16(Waa[(size_t)(kb + 2) * NH + c1], Waa[(size_t)(kb + 3) * NH + c1]);
            v1.z = pk16(Waa[(size_t)(kb + 4) * NH + c1], Waa[(size_t)(kb + 5) * NH + c1]);
            v1.w = pk16(Waa[(size_t)(kb + 6) * NH + c1], Waa[(size_t)(kb + 7) * NH + c1]);
            br0[kk] = v0;
            br1[kk] = v1;
        }
#pragma unroll
        for (int kk = 0; kk < LKT; ++kk) {
            const int kb = (RKT + kk) * 32 + 8 * q;
            uint4 v0, v1;
            v0.x = pk16(Waa[(size_t)(kb + 0) * NH + c0], Waa[(size_t)(kb + 1) * NH + c0]);
            v0.y = pk16(Waa[(size_t)(kb + 2) * NH + c0], Waa[(size_t)(kb + 3) * NH + c0]);
            v0.z = pk16(Waa[(size_t)(kb + 4) * NH + c0], Waa[(size_t)(kb + 5) * NH + c0]);
            v0.w = pk16(Waa[(size_t)(kb + 6) * NH + c0], Waa[(size_t)(kb + 7) * NH + c0]);
            v1.x = pk16(Waa[(size_t)(kb + 0) * NH + c1], Waa[(size_t)(kb + 1) * NH + c1]);
            v1.y = pk16(Waa[(size_t)(kb + 2) * NH + c1], Waa[(size_t)(kb + 3) * NH + c1]);
            v1.z = pk16(Waa[(size_t)(kb + 4) * NH + c1], Waa[(size_t)(kb + 5) * NH + c1]);
            v1.w = pk16(Waa[(size_t)(kb + 6) * NH + c1], Waa[(size_t)(kb + 7) * NH + c1]);
            wldsA[kk * 2 + 0][tid] = v0;
            wldsA[kk * 2 + 1][tid] = v1;
        }
        __syncthreads();                     // matches dot2 branch's sync

        const float* ub0 = out + (size_t)b * NH + c0;
        const float* ub1 = out + (size_t)b * NH + c1;
        float u0 = ub0[0], u1 = ub1[0];

        for (int t = 0; t < TT; ++t) {
            const int tn = (t + 1 < TT) ? (t + 1) : (TT - 1);
            float un0 = ub0[(size_t)tn * (BB * NH)];
            float un1 = ub1[(size_t)tn * (BB * NH)];

            const unsigned short* ac = a_h[t & 1];
            f32x4 acc0 = {}, acc1 = {};
#pragma unroll
            for (int kk = 0; kk < 16; ++kk) {
                uint4 av = *(const uint4*)&ac[kk * 32 + q * 8];
                half8_t A = __builtin_bit_cast(half8_t, av);
                uint4 b0, b1;
                if (kk < RKT) {
                    b0 = br0[kk];
                    b1 = br1[kk];
                } else {
                    b0 = wldsA[(kk - RKT) * 2 + 0][tid];
                    b1 = wldsA[(kk - RKT) * 2 + 1][tid];
                }
                acc0 = __builtin_amdgcn_mfma_f32_16x16x32_f16(
                    A, __builtin_bit_cast(half8_t, b0), acc0, 0, 0, 0);
                acc1 = __builtin_amdgcn_mfma_f32_16x16x32_f16(
                    A, __builtin_bit_cast(half8_t, b1), acc1, 0, 0, 0);
            }

            float an0 = tanh_fast(u0 + acc0[0]);
            float an1 = tanh_fast(u1 + acc1[0]);

            unsigned short* an = a_h[(t + 1) & 1];
            if (l < 16) {
                an[c0] = __builtin_bit_cast(unsigned short, (_Float16)an0);
                an[c1] = __builtin_bit_cast(unsigned short, (_Float16)an1);
                out[(size_t)t * (BB * NH) + (size_t)b * NH + c0] = an0;
                out[(size_t)t * (BB * NH) + (size_t)b * NH + c1] = an1;
            }
            u0 = un0;
            u1 = un1;
            __builtin_amdgcn_s_waitcnt(0xC07F);   // lgkmcnt(0)
            __builtin_amdgcn_s_barrier();         // barrier A
            __builtin_amdgcn_s_barrier();         // barrier B
        }
    } else {
        // ================= dot2 half: cols 256..511 =================
        const int t2   = tid - 512;
        const int kq   = t2 >> 6;            // k-eighth 0..7 (wave-uniform)
        const int cidx = t2 & 63;
        const int h4   = 256 + cidx * 4;     // 4 adjacent columns
        const int l32  = t2 & 31;

        unsigned w0[NRP], w1[NRP], w2r[NRP], w3[NRP];
#pragma unroll
        for (int j = 0; j < NRP; ++j) {
            const int k = kq * 64 + 2 * j;
            float4 r0 = *(const float4*)&Waa[(size_t)k       * NH + h4];
            float4 r1 = *(const float4*)&Waa[(size_t)(k + 1) * NH + h4];
            w0[j]  = pk16(r0.x, r1.x);
            w1[j]  = pk16(r0.y, r1.y);
            w2r[j] = pk16(r0.z, r1.z);
            w3[j]  = pk16(r0.w, r1.w);
        }
#pragma unroll
        for (int p = 0; p < NLP; ++p) {
            const int k = kq * 64 + 2 * (NRP + p);
            float4 r0 = *(const float4*)&Waa[(size_t)k       * NH + h4];
            float4 r1 = *(const float4*)&Waa[(size_t)(k + 1) * NH + h4];
            uint4 wv;
            wv.x = pk16(r0.x, r1.x);
            wv.y = pk16(r0.y, r1.y);
            wv.z = pk16(r0.z, r1.z);
            wv.w = pk16(r0.w, r1.w);
            wlds2[p][t2] = wv;
        }
        __syncthreads();                     // matches MFMA branch's sync

        const bool red = (t2 < 256);         // waves 8-11 reduce
        const int  hc  = 256 + (t2 & 255);   // reduce column (valid when red)
        float* ob = out + (size_t)b * NH + hc;
        float u_cur = red ? ob[0] : 0.0f;

        for (int t = 0; t < TT; ++t) {
            const int tn = (t + 1 < TT) ? (t + 1) : (TT - 1);
            float u_next = red ? ob[(size_t)tn * (BB * NH)] : 0.0f;

            // a-pair for this lane: halves [kq*64 + 2*l32, +1]
            unsigned a_loc = ((const unsigned*)a_h[t & 1])[kq * 32 + l32];

            float acc0 = 0.f, acc1 = 0.f, acc2 = 0.f, acc3 = 0.f;
#pragma unroll
            for (int j = 0; j < NRP; j += 2) {
                unsigned ra = bline(a_loc, j);
                unsigned rb = bline(a_loc, j + 1);
                acc0 = dot2u(w0[j],  ra, acc0);
                acc1 = dot2u(w1[j],  ra, acc1);
                acc2 = dot2u(w2r[j], ra, acc2);
                acc3 = dot2u(w3[j],  ra, acc3);
                acc0 = dot2u(w0[j + 1],  rb, acc0);
                acc1 = dot2u(w1[j + 1],  rb, acc1);
                acc2 = dot2u(w2r[j + 1], rb, acc2);
                acc3 = dot2u(w3[j + 1],  rb, acc3);
            }
#pragma unroll
            for (int p = 0; p < NLP; ++p) {
                unsigned ra = bline(a_loc, NRP + p);
                uint4 v = wlds2[p][t2];
                acc0 = dot2u(v.x, ra, acc0);
                acc1 = dot2u(v.y, ra, acc1);
                acc2 = dot2u(v.z, ra, acc2);
                acc3 = dot2u(v.w, ra, acc3);
            }

            float4 pv; pv.x = acc0; pv.y = acc1; pv.z = acc2; pv.w = acc3;
            *(float4*)&part[kq][cidx * 4] = pv;
            __builtin_amdgcn_s_waitcnt(0xC07F);   // lgkmcnt(0)
            __builtin_amdgcn_s_barrier();         // barrier A

            if (red) {
                const int j = t2 & 255;
                float x = u_cur +
                    (((part[0][j] + part[1][j]) + (part[2][j] + part[3][j])) +
                     ((part[4][j] + part[5][j]) + (part[6][j] + part[7][j])));
                float an = tanh_fast(x);
                ob[(size_t)t * (BB * NH)] = an;
                a_h[(t + 1) & 1][hc] =
                    __builtin_bit_cast(unsigned short, (_Float16)an);
            }
            u_cur = u_next;
            __builtin_amdgcn_s_waitcnt(0xC07F);   // lgkmcnt(0)
            __builtin_amdgcn_s_barrier();         // barrier B
        }
    }
}

extern "C" void kernel_launch(void* const* d_in, const int* in_sizes, int n_in,
                              void* d_out, int out_size, void* d_ws, size_t ws_size,
                              hipStream_t stream) {
    const float* X   = (const float*)d_in[0];
    const float* Wax = (const float*)d_in[1];
    const float* Waa = (const float*)d_in[2];
    const float* bx  = (const float*)d_in[3];
    const float* ba  = (const float*)d_in[4];
    float* out = (float*)d_out;

    const size_t xp_dw = (size_t)BB * (NIN / 2) * TT;
    const size_t wp_dw = (size_t)(NIN / 2) * NH;
    const size_t need  = (xp_dw + wp_dw) * sizeof(unsigned);

    if (ws_size >= need) {
        unsigned* Xp = (unsigned*)d_ws;
        unsigned* Wp = Xp + xp_dw;
        const int npack = (NX4 + NW4 + 255) / 256;
        pack_f16<<<npack, 256, 0, stream>>>(X, Wax, Xp, Wp);
        dim3 g1(NH / 128, TT / 128, BB);
        inp_proj_mfma_pk<<<g1, 256, 0, stream>>>(Xp, Wp, bx, ba, out);
    } else {
        dim3 g1(NH / 128, TT / 128, BB);
        inp_proj_mfma<<<g1, 256, 0, stream>>>(X, Wax, bx, ba, out);
    }
    rnn_scan_v10<<<BB, 1024, 0, stream>>>(Waa, out);
}